// Round 3
// baseline (1536.043 us; speedup 1.0000x reference)
//
#include <hip/hip_runtime.h>
#include <hip/hip_bf16.h>
#include <math.h>

#define N_NODES 8192
#define N_EDGES 262144
#define EP (N_EDGES + N_NODES)   // 270336 edges incl. self-loops
#define SLOPE 0.2f

// ---------------------------------------------------------------- edge_index decode
// Reference dtype is int64; harness may deliver int32 or raw int64. For int64,
// int32 view is [v0,0,v1,0,...] (v < 8192). Detect: odd words all zero.
__global__ void detect_i64(const int* __restrict__ raw, int* __restrict__ flag) {
    if (threadIdx.x == 0 && blockIdx.x == 0) {
        int acc = 0;
        for (int i = 0; i < 64; ++i) acc |= raw[2 * i + 1];
        *flag = (acc == 0) ? 1 : 0;   // 1 => int64
    }
}

__global__ void extract_edges(const int* __restrict__ raw, const int* __restrict__ flag,
                              int* __restrict__ esrc, int* __restrict__ edst) {
    int k = blockIdx.x * blockDim.x + threadIdx.x;
    if (k >= N_EDGES) return;
    if (*flag) {
        esrc[k] = raw[2 * (size_t)k];
        edst[k] = raw[2 * ((size_t)N_EDGES + k)];
    } else {
        esrc[k] = raw[k];
        edst[k] = raw[N_EDGES + k];
    }
}

// ---------------------------------------------------------------- CSR build

__global__ void hist_k(const int* __restrict__ edst, int* __restrict__ counts) {
    int k = blockIdx.x * blockDim.x + threadIdx.x;
    if (k >= EP) return;
    int d = (k < N_EDGES) ? edst[k] : (k - N_EDGES);
    atomicAdd(&counts[d], 1);
}

// exclusive scan of 8192 counts with a single 256-thread block
__global__ void scan_k(const int* __restrict__ counts, int* __restrict__ row_ptr) {
    __shared__ int part[256];
    int t = threadIdx.x;
    int base = t * 32;
    int loc[32];
    int s = 0;
    for (int i = 0; i < 32; ++i) { loc[i] = s; s += counts[base + i]; }
    part[t] = s;
    __syncthreads();
    for (int off = 1; off < 256; off <<= 1) {
        int tmp = (t >= off) ? part[t - off] : 0;
        __syncthreads();
        part[t] += tmp;
        __syncthreads();
    }
    int incl = part[t];
    int excl = incl - s;
    for (int i = 0; i < 32; ++i) row_ptr[base + i] = excl + loc[i];
    if (t == 255) row_ptr[N_NODES] = incl;
}

__global__ void scatter_k(const int* __restrict__ esrc, const int* __restrict__ edst,
                          const int* __restrict__ row_ptr, int* __restrict__ cursor,
                          int* __restrict__ ssrc, int* __restrict__ sdst) {
    int k = blockIdx.x * blockDim.x + threadIdx.x;
    if (k >= EP) return;
    int s, d;
    if (k < N_EDGES) { s = esrc[k]; d = edst[k]; }
    else             { s = d = k - N_EDGES; }
    int pos = row_ptr[d] + atomicAdd(&cursor[d], 1);
    ssrc[pos] = s;
    sdst[pos] = d;
}

// ---------------------------------------------------------------- GEMM (C = A * B^T)
// A: [M,K] f32 row-major, B: [Nc,K] f32 row-major, C: [M,Nc] f32
// mode 0: plain store;  mode 1: sigmoid epilogue
__global__ __launch_bounds__(256) void gemm_nt(const float* __restrict__ A,
                                               const float* __restrict__ B,
                                               float* __restrict__ C,
                                               int M, int Nc, int K, int mode) {
    __shared__ float As[16 * 65];
    __shared__ float Bs[16 * 65];
    int tid = threadIdx.x;
    int tx = tid & 15, ty = tid >> 4;
    int i0 = blockIdx.y * 64, j0 = blockIdx.x * 64;
    float acc[4][4] = {};
    for (int k0 = 0; k0 < K; k0 += 16) {
        for (int idx = tid; idx < 1024; idx += 256) {
            int r = idx >> 4, c = idx & 15;
            As[c * 65 + r] = A[(size_t)(i0 + r) * K + k0 + c];
            Bs[c * 65 + r] = B[(size_t)(j0 + r) * K + k0 + c];
        }
        __syncthreads();
        for (int kk = 0; kk < 16; ++kk) {
            float a[4], b[4];
#pragma unroll
            for (int u = 0; u < 4; ++u) a[u] = As[kk * 65 + ty * 4 + u];
#pragma unroll
            for (int u = 0; u < 4; ++u) b[u] = Bs[kk * 65 + tx * 4 + u];
#pragma unroll
            for (int u = 0; u < 4; ++u)
#pragma unroll
                for (int v = 0; v < 4; ++v) acc[u][v] += a[u] * b[v];
        }
        __syncthreads();
    }
#pragma unroll
    for (int u = 0; u < 4; ++u) {
        int i = i0 + ty * 4 + u;
#pragma unroll
        for (int v = 0; v < 4; ++v) {
            int j = j0 + tx * 4 + v;
            size_t o = (size_t)i * Nc + j;
            float val = acc[u][v];
            if (mode == 1) val = 1.0f / (1.0f + expf(-val));
            C[o] = val;
        }
    }
}

// ---------------------------------------------------------------- edge logits
// one wave (64 lanes) per edge: e = att . leaky_relu(xl[src] + xr[dst])
__global__ void edge_logits(const int* __restrict__ ssrc, const int* __restrict__ sdst,
                            const float* __restrict__ xl, const float* __restrict__ xr,
                            const float* __restrict__ att, float* __restrict__ e,
                            int out_ch) {
    int gid = blockIdx.x * blockDim.x + threadIdx.x;
    int edge = gid >> 6;
    int lane = threadIdx.x & 63;
    if (edge >= EP) return;
    int s = ssrc[edge], d = sdst[edge];
    float sum = 0.0f;
    for (int c = lane; c < out_ch; c += 64) {
        float v = xl[(size_t)s * out_ch + c] + xr[(size_t)d * out_ch + c];
        v = (v > 0.0f) ? v : SLOPE * v;
        sum += v * att[c];
    }
#pragma unroll
    for (int off = 32; off > 0; off >>= 1) sum += __shfl_down(sum, off, 64);
    if (lane == 0) e[edge] = sum;
}

// ---------------------------------------------------------------- softmax + aggregate
// one block (256 threads) per destination node; relu + bias fused
__global__ __launch_bounds__(256) void aggregate(const int* __restrict__ row_ptr,
                                                 const int* __restrict__ ssrc,
                                                 const float* __restrict__ e,
                                                 const float* __restrict__ xl,
                                                 const float* __restrict__ bias,
                                                 float* __restrict__ outf,
                                                 int out_ch) {
    __shared__ float red[256];
    int d = blockIdx.x;
    int beg = row_ptr[d], end = row_ptr[d + 1];
    int t = threadIdx.x;

    float lm = -INFINITY;
    for (int p = beg + t; p < end; p += 256) lm = fmaxf(lm, e[p]);
    red[t] = lm;
    __syncthreads();
    for (int off = 128; off > 0; off >>= 1) {
        if (t < off) red[t] = fmaxf(red[t], red[t + off]);
        __syncthreads();
    }
    float m = red[0];
    __syncthreads();

    float ls = 0.0f;
    for (int p = beg + t; p < end; p += 256) ls += expf(e[p] - m);
    red[t] = ls;
    __syncthreads();
    for (int off = 128; off > 0; off >>= 1) {
        if (t < off) red[t] += red[t + off];
        __syncthreads();
    }
    float inv = 1.0f / red[0];

    if (t < out_ch) {
        float acc = 0.0f;
        for (int p = beg; p < end; ++p) {
            float alpha = expf(e[p] - m) * inv;
            int s = ssrc[p];
            acc += alpha * xl[(size_t)s * out_ch + t];
        }
        float v = acc + bias[t];
        outf[(size_t)d * out_ch + t] = fmaxf(v, 0.0f);
    }
}

// ---------------------------------------------------------------- host side

static inline int ceil_div(int a, int b) { return (a + b - 1) / b; }

extern "C" void kernel_launch(void* const* d_in, const int* in_sizes, int n_in,
                              void* d_out, int out_size, void* d_ws, size_t ws_size,
                              hipStream_t stream) {
    const float* x    = (const float*)d_in[0];
    const int*   eraw = (const int*)d_in[1];

    const float* wl[5], *wr[5], *att[5], *bia[5];
    for (int l = 0; l < 5; ++l) {
        wl[l]  = (const float*)d_in[2 + 4 * l + 0];
        wr[l]  = (const float*)d_in[2 + 4 * l + 1];
        att[l] = (const float*)d_in[2 + 4 * l + 2];
        bia[l] = (const float*)d_in[2 + 4 * l + 3];
    }
    const int och[5] = {128, 256, 128, 128, 256};
    const int ich[5] = {256, 128, 256, 256, 128};

    float* outp  = (float*)d_out;
    float* recon = outp;                          // [8192, 8192]
    float* xrec  = outp + (size_t)67108864;       // [8192, 256]
    float* zout  = outp + (size_t)69206016;       // [8192, 256]

    // ---------------- workspace layout
    float* W = (float*)d_ws;
    float* xl    = W + 0;            // 2097152 (max OC=256)
    float* xr    = W + 2097152;      // 2097152
    float* hbuf  = W + 4194304;      // 1048576
    float* rebuf = W + 5242880;      // 1048576
    float* xdbuf = W + 6291456;      // 1048576
    float* ebuf  = W + 7340032;      // 270336
    int*   I     = (int*)(W + 7610368);
    int* counts  = I;                // 8192
    int* cursor  = I + 8192;         // 8192
    int* row_ptr = I + 16384;        // 8193
    int* ssrc    = I + 24577;        // 270336
    int* sdst    = I + 294913;       // 270336
    int* esrc    = I + 565249;       // 262144
    int* edst    = I + 827393;       // 262144
    int* flag    = I + 1089537;      // 1

    // ---------------- edge decode + CSR build
    detect_i64<<<1, 64, 0, stream>>>(eraw, flag);
    extract_edges<<<ceil_div(N_EDGES, 256), 256, 0, stream>>>(eraw, flag, esrc, edst);
    hipMemsetAsync(counts, 0, 2 * 8192 * sizeof(int), stream);
    hist_k<<<ceil_div(EP, 256), 256, 0, stream>>>(edst, counts);
    scan_k<<<1, 256, 0, stream>>>(counts, row_ptr);
    scatter_k<<<ceil_div(EP, 256), 256, 0, stream>>>(esrc, edst, row_ptr, cursor, ssrc, sdst);

    // ---------------- GAT layers
    const float* lin[5] = {x,    hbuf, zout,  zout,  xdbuf};
    float*       lof[5] = {hbuf, zout, rebuf, xdbuf, xrec };

    for (int l = 0; l < 5; ++l) {
        int K = ich[l], OC = och[l];
        dim3 g(OC / 64, N_NODES / 64);
        gemm_nt<<<g, 256, 0, stream>>>(lin[l], wl[l], xl, N_NODES, OC, K, 0);
        gemm_nt<<<g, 256, 0, stream>>>(lin[l], wr[l], xr, N_NODES, OC, K, 0);

        edge_logits<<<ceil_div(EP * 64, 256), 256, 0, stream>>>(ssrc, sdst, xl, xr, att[l], ebuf, OC);
        aggregate<<<N_NODES, 256, 0, stream>>>(row_ptr, ssrc, ebuf, xl, bia[l], lof[l], OC);

        if (l == 2) {
            dim3 gr(N_NODES / 64, N_NODES / 64);
            gemm_nt<<<gr, 256, 0, stream>>>(rebuf, rebuf, recon, N_NODES, N_NODES, 128, 1);
        }
    }
}

// Round 4
// 1141.968 us; speedup vs baseline: 1.3451x; 1.3451x over previous
//
#include <hip/hip_runtime.h>
#include <hip/hip_bf16.h>
#include <math.h>

#define N_NODES 8192
#define N_EDGES 262144
#define EP (N_EDGES + N_NODES)   // 270336 edges incl. self-loops
#define SLOPE 0.2f

typedef short bf16x8 __attribute__((ext_vector_type(8)));   // 8 bf16 in 4 VGPRs
typedef float f32x4 __attribute__((ext_vector_type(4)));

// ---------------------------------------------------------------- edge_index decode
__global__ void detect_i64(const int* __restrict__ raw, int* __restrict__ flag) {
    if (threadIdx.x == 0 && blockIdx.x == 0) {
        int acc = 0;
        for (int i = 0; i < 64; ++i) acc |= raw[2 * i + 1];
        *flag = (acc == 0) ? 1 : 0;   // 1 => int64
    }
}

__global__ void extract_edges(const int* __restrict__ raw, const int* __restrict__ flag,
                              int* __restrict__ esrc, int* __restrict__ edst) {
    int k = blockIdx.x * blockDim.x + threadIdx.x;
    if (k >= N_EDGES) return;
    if (*flag) {
        esrc[k] = raw[2 * (size_t)k];
        edst[k] = raw[2 * ((size_t)N_EDGES + k)];
    } else {
        esrc[k] = raw[k];
        edst[k] = raw[N_EDGES + k];
    }
}

// ---------------------------------------------------------------- CSR build

__global__ void hist_k(const int* __restrict__ edst, int* __restrict__ counts) {
    int k = blockIdx.x * blockDim.x + threadIdx.x;
    if (k >= EP) return;
    int d = (k < N_EDGES) ? edst[k] : (k - N_EDGES);
    atomicAdd(&counts[d], 1);
}

__global__ void scan_k(const int* __restrict__ counts, int* __restrict__ row_ptr) {
    __shared__ int part[256];
    int t = threadIdx.x;
    int base = t * 32;
    int loc[32];
    int s = 0;
    for (int i = 0; i < 32; ++i) { loc[i] = s; s += counts[base + i]; }
    part[t] = s;
    __syncthreads();
    for (int off = 1; off < 256; off <<= 1) {
        int tmp = (t >= off) ? part[t - off] : 0;
        __syncthreads();
        part[t] += tmp;
        __syncthreads();
    }
    int incl = part[t];
    int excl = incl - s;
    for (int i = 0; i < 32; ++i) row_ptr[base + i] = excl + loc[i];
    if (t == 255) row_ptr[N_NODES] = incl;
}

__global__ void scatter_k(const int* __restrict__ esrc, const int* __restrict__ edst,
                          const int* __restrict__ row_ptr, int* __restrict__ cursor,
                          int* __restrict__ ssrc, int* __restrict__ sdst) {
    int k = blockIdx.x * blockDim.x + threadIdx.x;
    if (k >= EP) return;
    int s, d;
    if (k < N_EDGES) { s = esrc[k]; d = edst[k]; }
    else             { s = d = k - N_EDGES; }
    int pos = row_ptr[d] + atomicAdd(&cursor[d], 1);
    ssrc[pos] = s;
    sdst[pos] = d;
}

// ---------------------------------------------------------------- f32 -> bf16 bits
__global__ void cvt_f32_bf16(const float* __restrict__ in, unsigned short* __restrict__ out, int n) {
    int i = blockIdx.x * blockDim.x + threadIdx.x;
    if (i < n) {
        __hip_bfloat16 h = __float2bfloat16(in[i]);
        out[i] = *(unsigned short*)&h;
    }
}

// ---------------------------------------------------------------- layer GEMM (C = A * B^T), f32
__global__ __launch_bounds__(256) void gemm_nt(const float* __restrict__ A,
                                               const float* __restrict__ B,
                                               float* __restrict__ C,
                                               int M, int Nc, int K) {
    __shared__ float As[16 * 65];
    __shared__ float Bs[16 * 65];
    int tid = threadIdx.x;
    int tx = tid & 15, ty = tid >> 4;
    int i0 = blockIdx.y * 64, j0 = blockIdx.x * 64;
    float acc[4][4] = {};
    for (int k0 = 0; k0 < K; k0 += 16) {
        for (int idx = tid; idx < 1024; idx += 256) {
            int r = idx >> 4, c = idx & 15;
            As[c * 65 + r] = A[(size_t)(i0 + r) * K + k0 + c];
            Bs[c * 65 + r] = B[(size_t)(j0 + r) * K + k0 + c];
        }
        __syncthreads();
        for (int kk = 0; kk < 16; ++kk) {
            float a[4], b[4];
#pragma unroll
            for (int u = 0; u < 4; ++u) a[u] = As[kk * 65 + ty * 4 + u];
#pragma unroll
            for (int u = 0; u < 4; ++u) b[u] = Bs[kk * 65 + tx * 4 + u];
#pragma unroll
            for (int u = 0; u < 4; ++u)
#pragma unroll
                for (int v = 0; v < 4; ++v) acc[u][v] += a[u] * b[v];
        }
        __syncthreads();
    }
#pragma unroll
    for (int u = 0; u < 4; ++u) {
        int i = i0 + ty * 4 + u;
#pragma unroll
        for (int v = 0; v < 4; ++v) {
            C[(size_t)i * Nc + j0 + tx * 4 + v] = acc[u][v];
        }
    }
}

// ---------------------------------------------------------------- recon MFMA GEMM
// C[8192,8192] = sigmoid(R @ R^T), R bf16 [8192,128]. 128x128 tile, 4 waves,
// each wave a 64x64 quadrant of 4x4 16x16 MFMA tiles. K=128 in one LDS stage.
#define LSTR 136   // LDS row stride in bf16 units (pad 8 -> 2-way conflict only)

__global__ __launch_bounds__(256) void recon_mfma(const unsigned short* __restrict__ Rb,
                                                  float* __restrict__ C) {
    __shared__ __align__(16) short As[128 * LSTR];
    __shared__ __align__(16) short Bs[128 * LSTR];
    int tid = threadIdx.x;
    int i0 = blockIdx.y * 128, j0 = blockIdx.x * 128;
    const short* R = (const short*)Rb;
    // stage both tiles: 128 rows x 128 bf16 = 2048 16B-chunks -> 8 per thread
#pragma unroll
    for (int c = 0; c < 8; ++c) {
        int idx = tid + c * 256;
        int row = idx >> 4, col = (idx & 15) * 8;
        *(bf16x8*)(&As[row * LSTR + col]) = *(const bf16x8*)(&R[(size_t)(i0 + row) * 128 + col]);
        *(bf16x8*)(&Bs[row * LSTR + col]) = *(const bf16x8*)(&R[(size_t)(j0 + row) * 128 + col]);
    }
    __syncthreads();
    int wave = tid >> 6, lane = tid & 63;
    int wr = (wave >> 1) * 64, wc = (wave & 1) * 64;
    int lm = lane & 15, quad = lane >> 4;
    f32x4 acc[4][4] = {};
#pragma unroll
    for (int ks = 0; ks < 4; ++ks) {
        int ko = ks * 32 + quad * 8;
        bf16x8 a[4], b[4];
#pragma unroll
        for (int u = 0; u < 4; ++u)
            a[u] = *(const bf16x8*)(&As[(wr + u * 16 + lm) * LSTR + ko]);
#pragma unroll
        for (int v = 0; v < 4; ++v)
            b[v] = *(const bf16x8*)(&Bs[(wc + v * 16 + lm) * LSTR + ko]);
#pragma unroll
        for (int u = 0; u < 4; ++u)
#pragma unroll
            for (int v = 0; v < 4; ++v)
                acc[u][v] = __builtin_amdgcn_mfma_f32_16x16x32_bf16(a[u], b[v], acc[u][v], 0, 0, 0);
    }
    // C/D layout: col = lane&15, row = quad*4 + reg (m89/m91-verified)
#pragma unroll
    for (int u = 0; u < 4; ++u)
#pragma unroll
        for (int v = 0; v < 4; ++v)
#pragma unroll
            for (int r = 0; r < 4; ++r) {
                int row = i0 + wr + u * 16 + quad * 4 + r;
                int col = j0 + wc + v * 16 + lm;
                float val = acc[u][v][r];
                C[(size_t)row * 8192 + col] = 1.0f / (1.0f + __expf(-val));
            }
}

// ---------------------------------------------------------------- edge logits
__global__ void edge_logits(const int* __restrict__ ssrc, const int* __restrict__ sdst,
                            const float* __restrict__ xl, const float* __restrict__ xr,
                            const float* __restrict__ att, float* __restrict__ e,
                            int out_ch) {
    int gid = blockIdx.x * blockDim.x + threadIdx.x;
    int edge = gid >> 6;
    int lane = threadIdx.x & 63;
    if (edge >= EP) return;
    int s = ssrc[edge], d = sdst[edge];
    float sum = 0.0f;
    for (int c = lane; c < out_ch; c += 64) {
        float v = xl[(size_t)s * out_ch + c] + xr[(size_t)d * out_ch + c];
        v = (v > 0.0f) ? v : SLOPE * v;
        sum += v * att[c];
    }
#pragma unroll
    for (int off = 32; off > 0; off >>= 1) sum += __shfl_down(sum, off, 64);
    if (lane == 0) e[edge] = sum;
}

// ---------------------------------------------------------------- softmax + aggregate
// one block per node. alpha normalized in-place into e; accumulation chunked
// with LDS-staged (alpha, src) so the gathers are independent (ILP).
__global__ __launch_bounds__(256) void aggregate(const int* __restrict__ row_ptr,
                                                 const int* __restrict__ ssrc,
                                                 float* __restrict__ e,
                                                 const float* __restrict__ xl,
                                                 const float* __restrict__ bias,
                                                 float* __restrict__ outf,
                                                 int out_ch) {
    __shared__ float red[256];
    __shared__ float sal[64];
    __shared__ int   ssh[64];
    int d = blockIdx.x;
    int beg = row_ptr[d], end = row_ptr[d + 1];
    int t = threadIdx.x;

    float lm = -INFINITY;
    for (int p = beg + t; p < end; p += 256) lm = fmaxf(lm, e[p]);
    red[t] = lm;
    __syncthreads();
    for (int off = 128; off > 0; off >>= 1) {
        if (t < off) red[t] = fmaxf(red[t], red[t + off]);
        __syncthreads();
    }
    float m = red[0];
    __syncthreads();

    float ls = 0.0f;
    for (int p = beg + t; p < end; p += 256) ls += __expf(e[p] - m);
    red[t] = ls;
    __syncthreads();
    for (int off = 128; off > 0; off >>= 1) {
        if (t < off) red[t] += red[t + off];
        __syncthreads();
    }
    float inv = 1.0f / red[0];
    __syncthreads();

    // normalize alpha in place
    for (int p = beg + t; p < end; p += 256) e[p] = __expf(e[p] - m) * inv;
    __syncthreads();

    // chunked accumulate
    float acc = 0.0f;
    for (int cb = beg; cb < end; cb += 64) {
        int n = min(64, end - cb);
        if (t < n) { sal[t] = e[cb + t]; ssh[t] = ssrc[cb + t]; }
        __syncthreads();
        if (t < out_ch) {
            for (int i = 0; i < n; ++i)
                acc += sal[i] * xl[(size_t)ssh[i] * out_ch + t];
        }
        __syncthreads();
    }
    if (t < out_ch)
        outf[(size_t)d * out_ch + t] = fmaxf(acc + bias[t], 0.0f);
}

// ---------------------------------------------------------------- host side

static inline int ceil_div(int a, int b) { return (a + b - 1) / b; }

extern "C" void kernel_launch(void* const* d_in, const int* in_sizes, int n_in,
                              void* d_out, int out_size, void* d_ws, size_t ws_size,
                              hipStream_t stream) {
    const float* x    = (const float*)d_in[0];
    const int*   eraw = (const int*)d_in[1];

    const float* wl[5], *wr[5], *att[5], *bia[5];
    for (int l = 0; l < 5; ++l) {
        wl[l]  = (const float*)d_in[2 + 4 * l + 0];
        wr[l]  = (const float*)d_in[2 + 4 * l + 1];
        att[l] = (const float*)d_in[2 + 4 * l + 2];
        bia[l] = (const float*)d_in[2 + 4 * l + 3];
    }
    const int och[5] = {128, 256, 128, 128, 256};
    const int ich[5] = {256, 128, 256, 256, 128};

    float* outp  = (float*)d_out;
    float* recon = outp;                          // [8192, 8192]
    float* xrec  = outp + (size_t)67108864;       // [8192, 256]
    float* zout  = outp + (size_t)69206016;       // [8192, 256]

    // ---------------- workspace layout
    float* W = (float*)d_ws;
    float* xl    = W + 0;            // 2097152 (max OC=256)
    float* xr    = W + 2097152;      // 2097152
    float* hbuf  = W + 4194304;      // 1048576
    float* rebuf = W + 5242880;      // 1048576
    float* xdbuf = W + 6291456;      // 1048576
    float* ebuf  = W + 7340032;      // 270336
    int*   I     = (int*)(W + 7610368);
    int* counts  = I;                // 8192
    int* cursor  = I + 8192;         // 8192
    int* row_ptr = I + 16384;        // 8193
    int* ssrc    = I + 24577;        // 270336
    int* sdst    = I + 294913;       // 270336
    int* esrc    = I + 565249;       // 262144
    int* edst    = I + 827393;       // 262144
    int* flag    = I + 1089537;      // 1
    unsigned short* Rb = (unsigned short*)(I + 1089540);  // 1048576 bf16 (2 MB)

    // ---------------- edge decode + CSR build
    detect_i64<<<1, 64, 0, stream>>>(eraw, flag);
    extract_edges<<<ceil_div(N_EDGES, 256), 256, 0, stream>>>(eraw, flag, esrc, edst);
    hipMemsetAsync(counts, 0, 2 * 8192 * sizeof(int), stream);
    hist_k<<<ceil_div(EP, 256), 256, 0, stream>>>(edst, counts);
    scan_k<<<1, 256, 0, stream>>>(counts, row_ptr);
    scatter_k<<<ceil_div(EP, 256), 256, 0, stream>>>(esrc, edst, row_ptr, cursor, ssrc, sdst);

    // ---------------- GAT layers
    const float* lin[5] = {x,    hbuf, zout,  zout,  xdbuf};
    float*       lof[5] = {hbuf, zout, rebuf, xdbuf, xrec };

    for (int l = 0; l < 5; ++l) {
        int K = ich[l], OC = och[l];
        dim3 g(OC / 64, N_NODES / 64);
        gemm_nt<<<g, 256, 0, stream>>>(lin[l], wl[l], xl, N_NODES, OC, K);
        gemm_nt<<<g, 256, 0, stream>>>(lin[l], wr[l], xr, N_NODES, OC, K);

        edge_logits<<<ceil_div(EP * 64, 256), 256, 0, stream>>>(ssrc, sdst, xl, xr, att[l], ebuf, OC);
        aggregate<<<N_NODES, 256, 0, stream>>>(row_ptr, ssrc, ebuf, xl, bia[l], lof[l], OC);

        if (l == 2) {
            cvt_f32_bf16<<<ceil_div(N_NODES * 128, 256), 256, 0, stream>>>(rebuf, Rb, N_NODES * 128);
            dim3 gr(64, 64);
            recon_mfma<<<gr, 256, 0, stream>>>(Rb, recon);
        }
    }
}